// Round 3
// baseline (1583.310 us; speedup 1.0000x reference)
//
#include <hip/hip_runtime.h>
#include <hip/hip_bf16.h>
#include <cstddef>
#include <cstdint>

#define DEVINL __device__ __forceinline__

typedef unsigned short u16;
typedef __attribute__((ext_vector_type(8))) short short8;
typedef __attribute__((ext_vector_type(4))) float f32x4;

constexpr int NROW  = 32768;
constexpr int CHUNK = 4096;          // rows per L1->L2 chunk (8 chunks)

// ---------- ws byte offsets ----------
// weights (bf16 limb planes, 1,679,360 elems) @0 ; stats @3,358,720 (704 f32)
constexpr size_t WT_B    = 0;
constexpr size_t STATS_B = 3358720;
constexpr size_t X12H_B  = 3361792;    // N*704 bf16 hi planes (sec1+sec2)
constexpr size_t X12L_B  = 49499136;   // N*704 bf16 lo planes
constexpr size_t XH0_B   = 95636480;   // N*256 bf16 limb0 of x sec0
constexpr size_t XM0_B   = 112413696;  // limb1
constexpr size_t XL0_B   = 129190912;  // limb2
constexpr size_t H1_B    = 145968128;  // CHUNK*1920 bf16 (hi)
constexpr size_t H1L_B   = 161696768;  // CHUNK*1920 bf16 (lo)
// y overlays (valid once producers of the underlying data are done):
constexpr size_t Y0F_B   = 129190912;  // N*256 f32   (over xl0 + h1 head)
constexpr size_t Y1_B    = 95636480;   // N*384 bf16  (over xh0/xm0, after L3s0)
constexpr size_t Y2_B    = 162745344;  // N*320 bf16  (over h1 tail)
constexpr size_t WS_NEED = 183716864;

// weight limb-plane element offsets in WT
// L1s0 3-limb: h@0 m@131072 l@262144
// pairs (h,l): L1s1 393216/425984  L1s2 458752/466944
// L2s0 475136/737280  L2s1 999424/1064960  L2s2 1130496/1146880
// L3s0 1163264/1294336 L3s1 1425408/1458176 L3s2 1490944/1499136
// WBs0 1507328/1572864 WBs1 1638400/1654784 WBs2 1671168/1675264

DEVINL u16 f2bf(float f) {
    union { float f; unsigned u; } c; c.f = f;
    unsigned r = (c.u + 0x7fffu + ((c.u >> 16) & 1u)) >> 16;
    return (u16)r;
}
DEVINL float bf2f(u16 b) {
    union { unsigned u; float f; } c; c.u = ((unsigned)b) << 16;
    return c.f;
}
DEVINL short8 ld8(const u16* p) { return *(const short8*)p; }

// ---------------- prep: weights -> limb planes + zero stats ----------------
__global__ void k_prep(const float* __restrict__ w1, const float* __restrict__ w2,
                       const float* __restrict__ w3, const float* __restrict__ wb,
                       u16* __restrict__ WT, float* __restrict__ stats)
{
    int t = blockIdx.x * 256 + threadIdx.x;
    if (t < 774144) {
        const float i128 = 0.08838834764831845f, i512 = 0.044194173824159216f;
        const int   beg[12]  = {0,131072,163840,172032,434176,499712,516096,647168,679936,688128,753664,770048};
        const int   arr[12]  = {0,0,0,1,1,1,2,2,2,3,3,3};
        const int   srco[12] = {0,131072,163840,0,262144,327680,0,131072,163840,0,65536,81920};
        const int   mil[12]  = {8,7,6,9,8,7,9,8,7,8,7,6};
        const int   moA[12]  = {512,256,128,512,256,128,256,128,64,256,128,64};
        const int   dsth[12] = {0,393216,458752,475136,999424,1130496,1163264,1425408,1490944,1507328,1638400,1671168};
        const int   dstl[12] = {262144,425984,466944,737280,1064960,1146880,1294336,1458176,1499136,1572864,1654784,1675264};
        const float scl[12]  = {0.0625f,i128,0.125f,i512,0.0625f,i128,i512,0.0625f,i128,0.0625f,i128,0.125f};
        int s = 0;
        #pragma unroll
        for (int i = 1; i < 12; ++i) s += (t >= beg[i]) ? 1 : 0;
        int e  = t - beg[s];
        int mi = 1 << mil[s];
        int v  = e >> mil[s];
        int u  = e & (mi - 1);
        const float* srcs[4] = {w1, w2, w3, wb};
        float val = srcs[arr[s]][srco[s] + u * moA[s] + v] * scl[s];
        u16 h = f2bf(val);
        float r1 = val - bf2f(h);
        u16 m = f2bf(r1);
        WT[dsth[s] + e] = h;
        if (s == 0) {
            float r2 = r1 - bf2f(m);
            WT[131072 + e] = m;
            WT[262144 + e] = f2bf(r2);
        } else {
            WT[dstl[s] + e] = m;
        }
    } else {
        int q = t - 774144;
        if (q < 704) stats[q] = 0.f;
    }
}

// ---------------- x (f32, interleaved) -> limb planes ----------------
__global__ void k_xconv(const float* __restrict__ x,
                        u16* __restrict__ xh0, u16* __restrict__ xm0, u16* __restrict__ xl0,
                        u16* __restrict__ x12h, u16* __restrict__ x12l)
{
    int g = blockIdx.x * 256 + threadIdx.x;   // 3,932,160 groups of 8 elems
    float f[8];
    if (g < 1048576) {                         // sec0: m=256, l=0 -> 3 limbs
        int n = g >> 5, u0 = (g & 31) * 8;
        const float* s = x + (size_t)n * 960 + u0;
        float4 f0 = *(const float4*)s;
        float4 f1 = *(const float4*)(s + 4);
        f[0]=f0.x; f[1]=f0.y; f[2]=f0.z; f[3]=f0.w;
        f[4]=f1.x; f[5]=f1.y; f[6]=f1.z; f[7]=f1.w;
        short8 oh, om, ol;
        #pragma unroll
        for (int j = 0; j < 8; ++j) {
            u16 h = f2bf(f[j]);       float r1 = f[j] - bf2f(h);
            u16 m = f2bf(r1);         float r2 = r1 - bf2f(m);
            oh[j] = (short)h; om[j] = (short)m; ol[j] = (short)f2bf(r2);
        }
        size_t dof = (size_t)n * 256 + u0;
        *(short8*)(xh0 + dof) = oh;
        *(short8*)(xm0 + dof) = om;
        *(short8*)(xl0 + dof) = ol;
        return;
    }
    size_t dof;
    if (g < 2621440) {                         // sec1: m=128, l=1 -> 2 limbs
        int gl = g - 1048576;
        int i = gl >> 19, r = gl & 524287;
        int n = r >> 4, u0 = (r & 15) * 8;
        const float* s = x + (size_t)n * 960 + 256 + (size_t)u0 * 3 + i;
        #pragma unroll
        for (int j = 0; j < 8; ++j) f[j] = s[j * 3];
        dof = (size_t)i * 4194304 + (size_t)n * 128 + u0;
    } else {                                   // sec2: m=64, l=2 -> 2 limbs
        int gl = g - 2621440;
        int i = gl >> 18, r = gl & 262143;
        int n = r >> 3, u0 = (r & 7) * 8;
        const float* s = x + (size_t)n * 960 + 640 + (size_t)u0 * 5 + i;
        #pragma unroll
        for (int j = 0; j < 8; ++j) f[j] = s[j * 5];
        dof = 12582912 + (size_t)i * 2097152 + (size_t)n * 64 + u0;
    }
    short8 oh, ol;
    #pragma unroll
    for (int j = 0; j < 8; ++j) {
        u16 h = f2bf(f[j]);
        oh[j] = (short)h;
        ol[j] = (short)f2bf(f[j] - bf2f(h));
    }
    *(short8*)(x12h + dof) = oh;
    *(short8*)(x12l + dof) = ol;
}

#define MFMA __builtin_amdgcn_mfma_f32_16x16x32_bf16

// ---------------- generic GEMM core: 64x64 block, 4 waves of 32x32 ----------------
template<int C, int K, bool SPLIT>
DEVINL void gemm_core(const u16* __restrict__ Ah, const u16* __restrict__ Al, long aStride,
                      const u16* __restrict__ Bh, const u16* __restrict__ Bl,
                      int rb, int cb, f32x4 acc[C][2][2])
{
    int tix  = threadIdx.x;
    int lane = tix & 63, w = tix >> 6;
    int n0 = rb * 64 + (w >> 1) * 32;
    int v0 = cb * 64 + (w & 1) * 32;
    int col = lane & 15, kof = (lane >> 4) * 8;
    size_t aOff0 = (size_t)(n0 + col) * K + kof;
    size_t aOff1 = aOff0 + (size_t)16 * K;
    size_t bOff0 = (size_t)(v0 + col) * K + kof;
    size_t bOff1 = bOff0 + (size_t)16 * K;
    for (int ks = 0; ks < K; ks += 32) {
        short8 b0h = ld8(Bh + bOff0 + ks);
        short8 b1h = ld8(Bh + bOff1 + ks);
        short8 b0l, b1l;
        if constexpr (SPLIT) {
            b0l = ld8(Bl + bOff0 + ks);
            b1l = ld8(Bl + bOff1 + ks);
        }
        #pragma unroll
        for (int p = 0; p < C; ++p) {
            short8 a0h = ld8(Ah + (size_t)p * aStride + aOff0 + ks);
            short8 a1h = ld8(Ah + (size_t)p * aStride + aOff1 + ks);
            acc[p][0][0] = MFMA(a0h, b0h, acc[p][0][0], 0, 0, 0);
            acc[p][0][1] = MFMA(a0h, b1h, acc[p][0][1], 0, 0, 0);
            acc[p][1][0] = MFMA(a1h, b0h, acc[p][1][0], 0, 0, 0);
            acc[p][1][1] = MFMA(a1h, b1h, acc[p][1][1], 0, 0, 0);
            if constexpr (SPLIT) {
                short8 a0l = ld8(Al + (size_t)p * aStride + aOff0 + ks);
                short8 a1l = ld8(Al + (size_t)p * aStride + aOff1 + ks);
                acc[p][0][0] = MFMA(a0l, b0h, acc[p][0][0], 0, 0, 0);
                acc[p][0][0] = MFMA(a0h, b0l, acc[p][0][0], 0, 0, 0);
                acc[p][0][1] = MFMA(a0l, b1h, acc[p][0][1], 0, 0, 0);
                acc[p][0][1] = MFMA(a0h, b1l, acc[p][0][1], 0, 0, 0);
                acc[p][1][0] = MFMA(a1l, b0h, acc[p][1][0], 0, 0, 0);
                acc[p][1][0] = MFMA(a1h, b0l, acc[p][1][0], 0, 0, 0);
                acc[p][1][1] = MFMA(a1l, b1h, acc[p][1][1], 0, 0, 0);
                acc[p][1][1] = MFMA(a1h, b1l, acc[p][1][1], 0, 0, 0);
            }
        }
    }
}

template<int C, bool ACT, bool SOUT, bool OUTF32>
DEVINL void epilogue(f32x4 acc[C][2][2], u16* __restrict__ outH, u16* __restrict__ outL,
                     float* __restrict__ outF, long outStride, int MO, int rb, int cb)
{
    int tix  = threadIdx.x;
    int lane = tix & 63, w = tix >> 6;
    int n0 = rb * 64 + (w >> 1) * 32;
    int v0 = cb * 64 + (w & 1) * 32;
    int col = lane & 15, rb4 = (lane >> 4) * 4;
    #pragma unroll
    for (int tm = 0; tm < 2; ++tm) {
        #pragma unroll
        for (int r = 0; r < 4; ++r) {
            size_t nrow = (size_t)(n0 + tm * 16 + rb4 + r) * MO;
            #pragma unroll
            for (int tn = 0; tn < 2; ++tn) {
                int v = v0 + tn * 16 + col;
                float scl = 1.0f;
                if (ACT) {
                    float s2 = 1e-8f;
                    #pragma unroll
                    for (int p = 0; p < C; ++p) { float t = acc[p][tm][tn][r]; s2 += t * t; }
                    float nrm = sqrtf(s2);
                    scl = 1.0f / ((1.0f + __expf(-nrm)) * nrm);   // sigmoid(n)/n
                }
                #pragma unroll
                for (int p = 0; p < C; ++p) {
                    float val = acc[p][tm][tn][r] * scl;
                    if (OUTF32) {
                        outF[(size_t)p * outStride + nrow + v] = val;
                    } else {
                        u16 hi = f2bf(val);
                        outH[(size_t)p * outStride + nrow + v] = hi;
                        if (SOUT)
                            outL[(size_t)p * outStride + nrow + v] = f2bf(val - bf2f(hi));
                    }
                }
            }
        }
    }
}

template<int C, int K1, int K2, bool ACT, bool SIN1, bool SIN2, bool OUTF32, bool SOUT>
__global__ __launch_bounds__(256) void k_gemm(
    const u16* __restrict__ inH, const u16* __restrict__ inL, long inStride,
    const u16* __restrict__ in2H, const u16* __restrict__ in2L, long in2Stride,
    const u16* __restrict__ B1h, const u16* __restrict__ B1l,
    const u16* __restrict__ B2h, const u16* __restrict__ B2l,
    u16* __restrict__ outH, u16* __restrict__ outL, float* __restrict__ outF,
    long outStride, int MO, int cbs)
{
    int b = blockIdx.x;
    int xcd = b & 7, j = b >> 3;
    int rb = xcd + ((j >> cbs) << 3);
    int cb = j & ((1 << cbs) - 1);

    f32x4 acc[C][2][2];
    f32x4 z = {0.f, 0.f, 0.f, 0.f};
    #pragma unroll
    for (int p = 0; p < C; ++p)
        #pragma unroll
        for (int i = 0; i < 2; ++i)
            #pragma unroll
            for (int jj = 0; jj < 2; ++jj) acc[p][i][jj] = z;

    gemm_core<C, K1, SIN1>(inH, inL, inStride, B1h, B1l, rb, cb, acc);
    if constexpr (K2 > 0)
        gemm_core<C, K2, SIN2>(in2H, in2L, in2Stride, B2h, B2l, rb, cb, acc);
    epilogue<C, ACT, SOUT, OUTF32>(acc, outH, outL, outF, outStride, MO, rb, cb);
}

// ---------------- L1 sec0: 3-limb operands + compensated (TwoSum) accumulation ----------------
__global__ __launch_bounds__(256) void k_gemm_l1s0(
    const u16* __restrict__ Ah, const u16* __restrict__ Am, const u16* __restrict__ Al,
    const u16* __restrict__ Bh, const u16* __restrict__ Bm, const u16* __restrict__ Bl,
    u16* __restrict__ outH, u16* __restrict__ outL, int cbs)
{
    constexpr int K = 256;
    int b = blockIdx.x;
    int xcd = b & 7, j = b >> 3;
    int rb = xcd + ((j >> cbs) << 3);
    int cb = j & ((1 << cbs) - 1);

    int tix  = threadIdx.x;
    int lane = tix & 63, w = tix >> 6;
    int n0 = rb * 64 + (w >> 1) * 32;
    int v0 = cb * 64 + (w & 1) * 32;
    int col = lane & 15, kof = (lane >> 4) * 8;
    size_t aOff0 = (size_t)(n0 + col) * K + kof;
    size_t aOff1 = aOff0 + (size_t)16 * K;
    size_t bOff0 = (size_t)(v0 + col) * K + kof;
    size_t bOff1 = bOff0 + (size_t)16 * K;

    f32x4 z = {0.f, 0.f, 0.f, 0.f};
    f32x4 S[2][2], E[2][2], Cc[2][2];
    #pragma unroll
    for (int i = 0; i < 2; ++i)
        #pragma unroll
        for (int jj = 0; jj < 2; ++jj) { S[i][jj] = z; E[i][jj] = z; Cc[i][jj] = z; }

    for (int ks = 0; ks < K; ks += 32) {
        short8 bh[2], bm[2], bl[2], ah[2], am[2], al[2];
        bh[0] = ld8(Bh + bOff0 + ks); bh[1] = ld8(Bh + bOff1 + ks);
        bm[0] = ld8(Bm + bOff0 + ks); bm[1] = ld8(Bm + bOff1 + ks);
        bl[0] = ld8(Bl + bOff0 + ks); bl[1] = ld8(Bl + bOff1 + ks);
        ah[0] = ld8(Ah + aOff0 + ks); ah[1] = ld8(Ah + aOff1 + ks);
        am[0] = ld8(Am + aOff0 + ks); am[1] = ld8(Am + aOff1 + ks);
        al[0] = ld8(Al + aOff0 + ks); al[1] = ld8(Al + aOff1 + ks);
        #pragma unroll
        for (int i = 0; i < 2; ++i) {
            #pragma unroll
            for (int jj = 0; jj < 2; ++jj) {
                // corrections (chained, small magnitudes)
                f32x4 c = Cc[i][jj];
                c = MFMA(al[i], bh[jj], c, 0, 0, 0);
                c = MFMA(am[i], bm[jj], c, 0, 0, 0);
                c = MFMA(ah[i], bl[jj], c, 0, 0, 0);
                c = MFMA(am[i], bh[jj], c, 0, 0, 0);
                c = MFMA(ah[i], bm[jj], c, 0, 0, 0);
                Cc[i][jj] = c;
                // main product, unchained, folded via TwoSum
                f32x4 d = MFMA(ah[i], bh[jj], z, 0, 0, 0);
                #pragma unroll
                for (int r = 0; r < 4; ++r) {
                    float a = S[i][jj][r], bb = d[r];
                    float s = a + bb;
                    float t = s - a;
                    float err = (a - (s - t)) + (bb - t);
                    S[i][jj][r] = s;
                    E[i][jj][r] += err;
                }
            }
        }
    }

    // epilogue: p = S + (E + Cc); scalar norm-act (precise exp); split store
    int rb4 = (lane >> 4) * 4;
    #pragma unroll
    for (int tm = 0; tm < 2; ++tm) {
        #pragma unroll
        for (int r = 0; r < 4; ++r) {
            size_t nrow = (size_t)(n0 + tm * 16 + rb4 + r) * 512;
            #pragma unroll
            for (int tn = 0; tn < 2; ++tn) {
                int v = v0 + tn * 16 + col;
                float p = S[tm][tn][r] + (E[tm][tn][r] + Cc[tm][tn][r]);
                float nrm = sqrtf(p * p + 1e-8f);
                float sig = 1.0f / (1.0f + expf(-nrm));
                float val = p * (sig / nrm);
                u16 hi = f2bf(val);
                outH[nrow + v] = hi;
                outL[nrow + v] = f2bf(val - bf2f(hi));
            }
        }
    }
}

// ---------------- BN stats ----------------
__global__ void k_stats(const float* __restrict__ y0f, const u16* __restrict__ y1,
                        const u16* __restrict__ y2, float* __restrict__ stats)
{
    int sec = blockIdx.y, t = threadIdx.x;
    int r0 = blockIdx.x * 512;
    float sm = 0.f, sq = 0.f;
    if (sec == 0) {
        int v = t;            // 256 ch, step 1
        for (int r = r0; r < r0 + 512; ++r) {
            float val = y0f[(size_t)r * 256 + v];
            sm += val; sq += val * val;
        }
        atomicAdd(&stats[v], sm);
        atomicAdd(&stats[256 + v], sq);
    } else if (sec == 1) {
        int v = t & 127, sub = t >> 7;          // 2 subs
        for (int r = r0 + sub; r < r0 + 512; r += 2)
            #pragma unroll
            for (int p = 0; p < 3; ++p) {
                float val = bf2f(y1[(size_t)p * 4194304 + (size_t)r * 128 + v]);
                sq += val * val;
            }
        __shared__ float S2[256];
        S2[t] = sq;
        __syncthreads();
        if (t < 128) atomicAdd(&stats[512 + v], sq + S2[t + 128]);
    } else {
        int v = t & 63, sub = t >> 6;           // 4 subs
        for (int r = r0 + sub; r < r0 + 512; r += 4)
            #pragma unroll
            for (int p = 0; p < 5; ++p) {
                float val = bf2f(y2[(size_t)p * 2097152 + (size_t)r * 64 + v]);
                sq += val * val;
            }
        __shared__ float S2[256];
        S2[t] = sq;
        __syncthreads();
        if (t < 64) atomicAdd(&stats[640 + v], sq + S2[t + 64] + S2[t + 128] + S2[t + 192]);
    }
}

// ---------------- BN apply ----------------
__global__ __launch_bounds__(448) void k_bnapply(
    const float* __restrict__ y0f, const u16* __restrict__ y1, const u16* __restrict__ y2,
    const float* __restrict__ stats, const float* __restrict__ bnw, const float* __restrict__ bnb,
    float* __restrict__ out)
{
    int n = blockIdx.x, t = threadIdx.x;
    const float invN = 1.f / 32768.f;
    if (t < 256) {
        float mu  = stats[t] * invN;
        float var = stats[256 + t] * invN - mu * mu;
        float a   = bnw[t] * rsqrtf(var + 1e-5f);
        float val = y0f[(size_t)n * 256 + t];
        out[(size_t)n * 960 + t] = (val - mu) * a + bnb[t];
    } else if (t < 384) {
        int v = t - 256;
        float a = bnw[256 + v] * rsqrtf(stats[512 + v] * (invN / 3.f) + 1e-5f);
        #pragma unroll
        for (int i = 0; i < 3; ++i)
            out[(size_t)n * 960 + 256 + v * 3 + i] =
                bf2f(y1[(size_t)i * 4194304 + (size_t)n * 128 + v]) * a;
    } else {
        int v = t - 384;
        float a = bnw[384 + v] * rsqrtf(stats[640 + v] * (invN / 5.f) + 1e-5f);
        #pragma unroll
        for (int i = 0; i < 5; ++i)
            out[(size_t)n * 960 + 640 + v * 5 + i] =
                bf2f(y2[(size_t)i * 2097152 + (size_t)n * 64 + v]) * a;
    }
}

extern "C" void kernel_launch(void* const* d_in, const int* in_sizes, int n_in,
                              void* d_out, int out_size, void* d_ws, size_t ws_size,
                              hipStream_t stream)
{
    const float* x   = (const float*)d_in[0];
    const float* w1  = (const float*)d_in[1];
    const float* w2  = (const float*)d_in[2];
    const float* w3  = (const float*)d_in[3];
    const float* wb  = (const float*)d_in[4];
    const float* bnw = (const float*)d_in[5];
    const float* bnb = (const float*)d_in[6];
    float* out = (float*)d_out;

    if (ws_size < WS_NEED) return;

    char* ws = (char*)d_ws;
    u16*   WT    = (u16*)(ws + WT_B);
    float* stats = (float*)(ws + STATS_B);
    u16*   x12h  = (u16*)(ws + X12H_B);
    u16*   x12l  = (u16*)(ws + X12L_B);
    u16*   xh0   = (u16*)(ws + XH0_B);
    u16*   xm0   = (u16*)(ws + XM0_B);
    u16*   xl0   = (u16*)(ws + XL0_B);
    u16*   h1h   = (u16*)(ws + H1_B);
    u16*   h1l   = (u16*)(ws + H1L_B);
    float* y0f   = (float*)(ws + Y0F_B);
    u16*   y1    = (u16*)(ws + Y1_B);
    u16*   y2    = (u16*)(ws + Y2_B);
    u16*   h2    = (u16*)d_out;      // d_out bytes reused as h2 scratch

    k_prep <<<3027, 256, 0, stream>>>(w1, w2, w3, wb, WT, stats);
    k_xconv<<<15360, 256, 0, stream>>>(x, xh0, xm0, xl0, x12h, x12l);

    for (int c = 0; c < NROW / CHUNK; ++c) {
        size_t r0 = (size_t)c * CHUNK;
        // ---- layer 1 (chunk rows -> h1 chunk planes, split out) ----
        k_gemm_l1s0<<<512, 256, 0, stream>>>(
            xh0 + r0 * 256, xm0 + r0 * 256, xl0 + r0 * 256,
            WT + 0, WT + 131072, WT + 262144,
            h1h, h1l, 3);
        k_gemm<3, 128, 0, true, true, false, false, true><<<256, 256, 0, stream>>>(
            x12h + r0 * 128, x12l + r0 * 128, 4194304, nullptr, nullptr, 0,
            WT + 393216, WT + 425984, nullptr, nullptr,
            h1h + 2097152, h1l + 2097152, nullptr, 1048576, 256, 2);
        k_gemm<5, 64, 0, true, true, false, false, true><<<128, 256, 0, stream>>>(
            x12h + 12582912 + r0 * 64, x12l + 12582912 + r0 * 64, 2097152, nullptr, nullptr, 0,
            WT + 458752, WT + 466944, nullptr, nullptr,
            h1h + 5242880, h1l + 5242880, nullptr, 524288, 128, 1);
        // ---- layer 2 (h1 chunk -> h2 global rows, single-bf16 out) ----
        k_gemm<1, 512, 0, true, true, false, false, false><<<512, 256, 0, stream>>>(
            h1h, h1l, 0, nullptr, nullptr, 0,
            WT + 475136, WT + 737280, nullptr, nullptr,
            h2 + r0 * 512, nullptr, nullptr, 0, 512, 3);
        k_gemm<3, 256, 0, true, true, false, false, false><<<256, 256, 0, stream>>>(
            h1h + 2097152, h1l + 2097152, 1048576, nullptr, nullptr, 0,
            WT + 999424, WT + 1064960, nullptr, nullptr,
            h2 + 16777216 + r0 * 256, nullptr, nullptr, 8388608, 256, 2);
        k_gemm<5, 128, 0, true, true, false, false, false><<<128, 256, 0, stream>>>(
            h1h + 5242880, h1l + 5242880, 524288, nullptr, nullptr, 0,
            WT + 1130496, WT + 1146880, nullptr, nullptr,
            h2 + 41943040 + r0 * 128, nullptr, nullptr, 4194304, 128, 1);
    }

    // ---- layer 3 + bypass (2-limb) ----
    // sec0 first (reads xh0/xm0, writes y0f over xl0/h1-head)
    k_gemm<1, 512, 256, false, false, true, true, false><<<2048, 256, 0, stream>>>(
        h2, nullptr, 0, xh0, xm0, 0,
        WT + 1163264, nullptr, WT + 1507328, WT + 1572864,
        nullptr, nullptr, y0f, 0, 256, 2);
    // sec1 (writes y1 over xh0/xm0 - safe after sec0 kernel completes)
    k_gemm<3, 256, 128, false, false, true, false, false><<<1024, 256, 0, stream>>>(
        h2 + 16777216, nullptr, 8388608, x12h, x12l, 4194304,
        WT + 1425408, nullptr, WT + 1638400, WT + 1654784,
        y1, nullptr, nullptr, 4194304, 128, 1);
    k_gemm<5, 128, 64, false, false, true, false, false><<<512, 256, 0, stream>>>(
        h2 + 41943040, nullptr, 4194304, x12h + 12582912, x12l + 12582912, 2097152,
        WT + 1490944, nullptr, WT + 1671168, WT + 1675264,
        y2, nullptr, nullptr, 2097152, 64, 0);

    k_stats  <<<dim3(64, 3), 256, 0, stream>>>(y0f, y1, y2, stats);
    k_bnapply<<<32768, 448, 0, stream>>>(y0f, y1, y2, stats, bnw, bnb, out);
}

// Round 6
// 1362.852 us; speedup vs baseline: 1.1618x; 1.1618x over previous
//
#include <hip/hip_runtime.h>
#include <cstddef>
#include <cstdint>

#define DEVINL __device__ __forceinline__
typedef unsigned short u16;
typedef __attribute__((ext_vector_type(8))) short short8;
typedef __attribute__((ext_vector_type(4))) float f32x4;
#define MFMA16 __builtin_amdgcn_mfma_f32_16x16x32_bf16

constexpr int NROW = 32768;
constexpr int CM   = 8192;           // chunk rows (4 chunks)

// ---------- ws byte offsets ----------
constexpr size_t WT_B    = 0;          // 1,507,328 u16
constexpr size_t STATS_B = 3014656;    // 704 f32
constexpr size_t XS0_B   = 3017728;    // [32768][768] u16  (xh|xm|xl)
constexpr size_t X1_B    = 53349376;   // [3][32768][256] u16 ([h|l])
constexpr size_t X2_B    = 103681024;  // [5][32768][128] u16 ([h|l])
constexpr size_t H1S0_B  = 145624064;  // [8192][1024] u16 ([h|l])
constexpr size_t H1S1_B  = 162401280;  // [3][8192][512] u16 ([h|l])
constexpr size_t H1S2_B  = 187567104;  // [5][8192][256] u16 ([h|l])
constexpr size_t Y0F_B   = 145624064;  // [32768][256] f32 (overlay, after chunk loop)
constexpr size_t Y1_B    = 179178496;  // [3][32768][128] bf16
constexpr size_t Y2_B    = 204344320;  // [5][32768][64] bf16
constexpr size_t WS_NEED = 225315840;  // known available: >=253,209,600 (round-0 ran)

// WT element offsets:
// W1s0@0 [512][768](3L)  W1s1@393216 [256][256](2L)  W1s2@458752 [128][128](2L)
// W2s0@475136 [512][1024](2L)  W2s1@999424 [256][512](2L)  W2s2@1130496 [128][256](2L)
// W3s0@1163264 [256][512](1L)  W3s1@1294336 [128][256](1L) W3s2@1327104 [64][128](1L)
// WBs0@1335296 [256][512](2L)  WBs1@1466368 [128][256](2L) WBs2@1499136 [64][128](2L)

DEVINL u16 f2bf(float f) { union { float f; unsigned u; } c; c.f = f;
    unsigned r = (c.u + 0x7fffu + ((c.u >> 16) & 1u)) >> 16; return (u16)r; }
DEVINL float bf2f(u16 b) { union { unsigned u; float f; } c; c.u = ((unsigned)b) << 16; return c.f; }
DEVINL short8 ld8(const u16* p) { return *(const short8*)p; }

DEVINL void gload16(const u16* g, u16* l) {
    __builtin_amdgcn_global_load_lds(
        (const __attribute__((address_space(1))) unsigned*)g,
        (__attribute__((address_space(3))) unsigned*)l, 16, 0, 0);
}

// ---------------- prep ----------------
__global__ void k_prep(const float* __restrict__ w1, const float* __restrict__ w2,
                       const float* __restrict__ w3, const float* __restrict__ wb,
                       u16* __restrict__ WT, float* __restrict__ stats)
{
    int t = blockIdx.x * 256 + threadIdx.x;
    if (t < 1507328) {
        const float iA = 0.08838834764831845f;   // 1/sqrt(128)
        const float iB = 0.044194173824159216f;  // 1/sqrt(512)
        const int   beg[12]  = {0,393216,458752,475136,999424,1130496,1163264,1294336,1327104,1335296,1466368,1499136};
        const int   rowW[12] = {768,256,128,1024,512,256,512,256,128,512,256,128};
        const int   l2K[12]  = {8,7,6,9,8,7,9,8,7,8,7,6};
        const int   srco[12] = {0,131072,163840,0,262144,327680,0,131072,163840,0,65536,81920};
        const int   arr[12]  = {0,0,0,1,1,1,2,2,2,3,3,3};
        const int   ld[12]   = {512,256,128,512,256,128,256,128,64,256,128,64};
        const float scl[12]  = {0.0625f,iA,0.125f,iB,0.0625f,iA,iB,0.0625f,iA,0.0625f,iA,0.125f};
        int s = 0;
        #pragma unroll
        for (int i = 1; i < 12; ++i) s += (t >= beg[i]) ? 1 : 0;
        int e    = t - beg[s];
        int v    = e / rowW[s];
        int rem  = e - v * rowW[s];
        int limb = rem >> l2K[s];
        int u    = rem & ((1 << l2K[s]) - 1);
        const float* srcs[4] = {w1, w2, w3, wb};
        float val = srcs[arr[s]][srco[s] + u * ld[s] + v] * scl[s];
        u16 h = f2bf(val);  float r1 = val - bf2f(h);
        u16 m = f2bf(r1);   float r2 = r1 - bf2f(m);
        WT[t] = (limb == 0) ? h : (limb == 1) ? m : f2bf(r2);
    } else {
        int q = t - 1507328;
        if (q < 704) stats[q] = 0.f;
    }
}

// ---------------- x -> limb planes ----------------
__global__ void k_xconv(const float* __restrict__ x, u16* __restrict__ xs0,
                        u16* __restrict__ x1, u16* __restrict__ x2)
{
    int g = blockIdx.x * 256 + threadIdx.x;   // 3,932,160 groups of 8
    if (g < 1048576) {                         // sec0: 3 limbs, row [h|m|l]
        int n = g >> 5, u0 = (g & 31) * 8;
        const float* s = x + (size_t)n * 960 + u0;
        float4 f0 = *(const float4*)s;
        float4 f1 = *(const float4*)(s + 4);
        float f[8] = {f0.x,f0.y,f0.z,f0.w,f1.x,f1.y,f1.z,f1.w};
        short8 oh, om, ol;
        #pragma unroll
        for (int j = 0; j < 8; ++j) {
            u16 h = f2bf(f[j]); float r1 = f[j] - bf2f(h);
            u16 m = f2bf(r1);   float r2 = r1 - bf2f(m);
            oh[j] = (short)h; om[j] = (short)m; ol[j] = (short)f2bf(r2);
        }
        size_t d = (size_t)n * 768 + u0;
        *(short8*)(xs0 + d) = oh;
        *(short8*)(xs0 + d + 256) = om;
        *(short8*)(xs0 + d + 512) = ol;
        return;
    }
    float f[8]; u16* dst; int halfW;
    if (g < 2621440) {                         // sec1: 2 limbs, row [h|l]
        int gl = g - 1048576;
        int i = gl >> 19, r = gl & 524287;
        int n = r >> 4, u0 = (r & 15) * 8;
        const float* s = x + (size_t)n * 960 + 256 + (size_t)u0 * 3 + i;
        #pragma unroll
        for (int j = 0; j < 8; ++j) f[j] = s[j * 3];
        dst = x1 + (size_t)i * 8388608 + (size_t)n * 256 + u0;
        halfW = 128;
    } else {                                   // sec2: 2 limbs
        int gl = g - 2621440;
        int i = gl >> 18, r = gl & 262143;
        int n = r >> 3, u0 = (r & 7) * 8;
        const float* s = x + (size_t)n * 960 + 640 + (size_t)u0 * 5 + i;
        #pragma unroll
        for (int j = 0; j < 8; ++j) f[j] = s[j * 5];
        dst = x2 + (size_t)i * 4194304 + (size_t)n * 128 + u0;
        halfW = 64;
    }
    short8 oh, ol;
    #pragma unroll
    for (int j = 0; j < 8; ++j) {
        u16 h = f2bf(f[j]);
        oh[j] = (short)h;
        ol[j] = (short)f2bf(f[j] - bf2f(h));
    }
    *(short8*)dst = oh;
    *(short8*)(dst + halfW) = ol;
}

// ---------------- GEMM: 128x(NT*32) tile, LDS-staged A, per-tile limb maps ----------------
// EP: 0=bf16  1=f32  2=sig bf16  3=sig split  4=plain split
template<int NT, int EP, bool TS, bool SEG2>
__global__ __launch_bounds__(256) void k_gemm(
    const u16* __restrict__ A1, long A1ps, int A1cmb, int A1rs,
    int K1, int k1t, int T1, unsigned a1map, unsigned b1map,
    const u16* __restrict__ B1, int B1rs,
    const u16* __restrict__ A2, long A2ps, int A2cmb, int A2rs,
    int K2, int k2t, unsigned a2map, unsigned b2map,
    const u16* __restrict__ B2, int B2rs,
    int Stot, int tsTiles,
    u16* __restrict__ outB, float* __restrict__ outF,
    long Ops, int Ocmb, int Ors, int loOff, int cbs)
{
    constexpr int BN = NT * 32;
    __shared__ u16 lds[2][128 * 64];

    int b = blockIdx.x;
    int xcd = b & 7, jj = b >> 3;
    int rb = xcd + ((jj >> cbs) << 3);
    int cb = jj & ((1 << cbs) - 1);
    int rb128 = rb << 7;

    int tix = threadIdx.x, lane = tix & 63, w = tix >> 6;
    int wm64 = (w >> 1) << 6;
    int wn = w & 1;

    const u16* a1row = A1 + (size_t)(rb128 >> A1cmb) * A1ps
                          + (size_t)(rb128 & ((1 << A1cmb) - 1)) * A1rs;
    const u16* a2row = nullptr;
    if constexpr (SEG2)
        a2row = A2 + (size_t)(rb128 >> A2cmb) * A2ps
                   + (size_t)(rb128 & ((1 << A2cmb) - 1)) * A2rs;

    auto stage = [&](int t, int buf) {
        const u16* art; int rs, col0;
        if (!SEG2 || t < T1) {
            int sg = t >> k1t, off = (t & ((1 << k1t) - 1)) << 6;
            art = a1row; rs = A1rs;
            col0 = (int)((a1map >> (2 * sg)) & 3u) * K1 + off;
        } else {
            int tt = t - T1;
            int sg = tt >> k2t, off = (tt & ((1 << k2t) - 1)) << 6;
            art = a2row; rs = A2rs;
            col0 = (int)((a2map >> (2 * sg)) & 3u) * K2 + off;
        }
        #pragma unroll
        for (int i = 0; i < 4; ++i) {
            int seg = (w << 2) | i;
            int tr  = (seg << 3) + (lane >> 3);
            int sl  = lane & 7;
            const u16* src = art + (size_t)tr * rs + col0 + ((sl ^ (tr & 7)) << 3);
            gload16(src, &lds[buf][seg * 512]);
        }
    };

    f32x4 z = {0.f, 0.f, 0.f, 0.f};
    f32x4 acc[4][NT], S[4][NT], E[4][NT];
    #pragma unroll
    for (int mt = 0; mt < 4; ++mt)
        #pragma unroll
        for (int nt = 0; nt < NT; ++nt) { acc[mt][nt] = z; if constexpr (TS) { S[mt][nt] = z; E[mt][nt] = z; } }

    stage(0, 0);
    asm volatile("s_waitcnt vmcnt(0)" ::: "memory");
    __syncthreads();

    int colbase = cb * BN + wn * (NT * 16) + (lane & 15);
    int cur = 0;
    for (int s = 0; s < Stot; ++s) {
        const u16* bp; int brs, bcol;
        if (!SEG2 || s < T1) {
            int sg = s >> k1t;
            bcol = (int)((b1map >> (2 * sg)) & 3u) * K1 + ((s & ((1 << k1t) - 1)) << 6);
            bp = B1; brs = B1rs;
        } else {
            int tt = s - T1; int sg = tt >> k2t;
            bcol = (int)((b2map >> (2 * sg)) & 3u) * K2 + ((tt & ((1 << k2t) - 1)) << 6);
            bp = B2; brs = B2rs;
        }
        short8 breg[NT][2];
        #pragma unroll
        for (int nt = 0; nt < NT; ++nt)
            #pragma unroll
            for (int h = 0; h < 2; ++h)
                breg[nt][h] = ld8(bp + (size_t)(colbase + nt * 16) * brs + bcol + h * 32 + ((lane >> 4) << 3));

        if (s + 1 < Stot) stage(s + 1, cur ^ 1);

        bool tsT = TS && (s < tsTiles);
        #pragma unroll
        for (int h = 0; h < 2; ++h) {
            short8 a[4];
            #pragma unroll
            for (int mt = 0; mt < 4; ++mt) {
                int tr = wm64 + mt * 16 + (lane & 15);
                int slot = h * 4 + (lane >> 4);
                a[mt] = *(const short8*)&lds[cur][tr * 64 + ((slot ^ (tr & 7)) << 3)];
            }
            if (tsT) {
                #pragma unroll
                for (int mt = 0; mt < 4; ++mt)
                    #pragma unroll
                    for (int nt = 0; nt < NT; ++nt) {
                        f32x4 d = MFMA16(a[mt], breg[nt][h], z, 0, 0, 0);
                        #pragma unroll
                        for (int r = 0; r < 4; ++r) {
                            float aa = S[mt][nt][r], bb = d[r];
                            float sm = aa + bb;
                            float tt2 = sm - aa;
                            float er = (aa - (sm - tt2)) + (bb - tt2);
                            S[mt][nt][r] = sm;
                            E[mt][nt][r] += er;
                        }
                    }
            } else {
                #pragma unroll
                for (int mt = 0; mt < 4; ++mt)
                    #pragma unroll
                    for (int nt = 0; nt < NT; ++nt)
                        acc[mt][nt] = MFMA16(a[mt], breg[nt][h], acc[mt][nt], 0, 0, 0);
            }
        }
        asm volatile("s_waitcnt vmcnt(0)" ::: "memory");
        __syncthreads();
        cur ^= 1;
    }

    size_t obase = (size_t)(rb128 >> Ocmb) * Ops + (size_t)(rb128 & ((1 << Ocmb) - 1)) * Ors;
    #pragma unroll
    for (int mt = 0; mt < 4; ++mt) {
        #pragma unroll
        for (int r = 0; r < 4; ++r) {
            int lrow = wm64 + mt * 16 + ((lane >> 4) << 2) + r;
            size_t ro = obase + (size_t)lrow * Ors;
            #pragma unroll
            for (int nt = 0; nt < NT; ++nt) {
                int colg = cb * BN + wn * (NT * 16) + nt * 16 + (lane & 15);
                float p = acc[mt][nt][r];
                if constexpr (TS) p = S[mt][nt][r] + (E[mt][nt][r] + p);
                if constexpr (EP == 1) {
                    outF[ro + colg] = p;
                } else {
                    float v = p;
                    if constexpr (EP == 2 || EP == 3) {
                        float nrm = sqrtf(p * p + 1e-8f);
                        v = p / ((1.0f + expf(-nrm)) * nrm);
                    }
                    u16 hi = f2bf(v);
                    outB[ro + colg] = hi;
                    if constexpr (EP == 3 || EP == 4)
                        outB[ro + colg + loOff] = f2bf(v - bf2f(hi));
                }
            }
        }
    }
}

// ---------------- norm-act for l>0 planes (split-aware, in place) ----------------
template<int C, bool SPL>
__global__ __launch_bounds__(256) void k_normact(u16* __restrict__ buf, long PS,
                                                 int l2g, int halfW, long total8)
{
    long idx = (long)blockIdx.x * 256 + threadIdx.x;
    if (idx >= total8) return;
    long r  = idx >> l2g;
    int  cg = (int)(idx & ((1 << l2g) - 1));
    int  W  = SPL ? (halfW << 1) : halfW;
    size_t off = (size_t)r * W + (size_t)cg * 8;
    float f[C][8];
    #pragma unroll
    for (int i = 0; i < C; ++i) {
        short8 h = ld8(buf + (size_t)i * PS + off);
        if constexpr (SPL) {
            short8 l = ld8(buf + (size_t)i * PS + off + halfW);
            #pragma unroll
            for (int j = 0; j < 8; ++j) f[i][j] = bf2f((u16)h[j]) + bf2f((u16)l[j]);
        } else {
            #pragma unroll
            for (int j = 0; j < 8; ++j) f[i][j] = bf2f((u16)h[j]);
        }
    }
    #pragma unroll
    for (int j = 0; j < 8; ++j) {
        float s2 = 1e-8f;
        #pragma unroll
        for (int i = 0; i < C; ++i) s2 += f[i][j] * f[i][j];
        float nrm = sqrtf(s2);
        float scl = 1.0f / ((1.0f + __expf(-nrm)) * nrm);
        #pragma unroll
        for (int i = 0; i < C; ++i) f[i][j] *= scl;
    }
    #pragma unroll
    for (int i = 0; i < C; ++i) {
        short8 oh, ol;
        #pragma unroll
        for (int j = 0; j < 8; ++j) {
            u16 hi = f2bf(f[i][j]);
            oh[j] = (short)hi;
            if constexpr (SPL) ol[j] = (short)f2bf(f[i][j] - bf2f(hi));
        }
        *(short8*)(buf + (size_t)i * PS + off) = oh;
        if constexpr (SPL) *(short8*)(buf + (size_t)i * PS + off + halfW) = ol;
    }
}

// ---------------- BN stats ----------------
__global__ void k_stats(const float* __restrict__ y0f, const u16* __restrict__ y1,
                        const u16* __restrict__ y2, float* __restrict__ stats)
{
    int sec = blockIdx.y, t = threadIdx.x;
    int r0 = blockIdx.x * 512;
    float sm = 0.f, sq = 0.f;
    if (sec == 0) {
        int v = t;
        for (int r = r0; r < r0 + 512; ++r) {
            float val = y0f[(size_t)r * 256 + v];
            sm += val; sq += val * val;
        }
        atomicAdd(&stats[v], sm);
        atomicAdd(&stats[256 + v], sq);
    } else if (sec == 1) {
        int v = t & 127, sub = t >> 7;
        for (int r = r0 + sub; r < r0 + 512; r += 2)
            #pragma unroll
            for (int p = 0; p < 3; ++p) {
                float val = bf2f(y1[(size_t)p * 4194304 + (size_t)r * 128 + v]);
                sq += val * val;
            }
        __shared__ float S2[256];
        S2[t] = sq; __syncthreads();
        if (t < 128) atomicAdd(&stats[512 + v], sq + S2[t + 128]);
    } else {
        int v = t & 63, sub = t >> 6;
        for (int r = r0 + sub; r < r0 + 512; r += 4)
            #pragma unroll
            for (int p = 0; p < 5; ++p) {
                float val = bf2f(y2[(size_t)p * 2097152 + (size_t)r * 64 + v]);
                sq += val * val;
            }
        __shared__ float S2[256];
        S2[t] = sq; __syncthreads();
        if (t < 64) atomicAdd(&stats[640 + v], sq + S2[t + 64] + S2[t + 128] + S2[t + 192]);
    }
}

// ---------------- BN apply ----------------
__global__ __launch_bounds__(448) void k_bnapply(
    const float* __restrict__ y0f, const u16* __restrict__ y1, const u16* __restrict__ y2,
    const float* __restrict__ stats, const float* __restrict__ bnw, const float* __restrict__ bnb,
    float* __restrict__ out)
{
    int n = blockIdx.x, t = threadIdx.x;
    const float invN = 1.f / 32768.f;
    if (t < 256) {
        float mu  = stats[t] * invN;
        float var = stats[256 + t] * invN - mu * mu;
        float a   = bnw[t] * rsqrtf(var + 1e-5f);
        out[(size_t)n * 960 + t] = (y0f[(size_t)n * 256 + t] - mu) * a + bnb[t];
    } else if (t < 384) {
        int v = t - 256;
        float a = bnw[256 + v] * rsqrtf(stats[512 + v] * (invN / 3.f) + 1e-5f);
        #pragma unroll
        for (int i = 0; i < 3; ++i)
            out[(size_t)n * 960 + 256 + v * 3 + i] =
                bf2f(y1[(size_t)i * 4194304 + (size_t)n * 128 + v]) * a;
    } else {
        int v = t - 384;
        float a = bnw[384 + v] * rsqrtf(stats[640 + v] * (invN / 5.f) + 1e-5f);
        #pragma unroll
        for (int i = 0; i < 5; ++i)
            out[(size_t)n * 960 + 640 + v * 5 + i] =
                bf2f(y2[(size_t)i * 2097152 + (size_t)n * 64 + v]) * a;
    }
}

extern "C" void kernel_launch(void* const* d_in, const int* in_sizes, int n_in,
                              void* d_out, int out_size, void* d_ws, size_t ws_size,
                              hipStream_t stream)
{
    const float* x   = (const float*)d_in[0];
    const float* w1  = (const float*)d_in[1];
    const float* w2  = (const float*)d_in[2];
    const float* w3  = (const float*)d_in[3];
    const float* wb  = (const float*)d_in[4];
    const float* bnw = (const float*)d_in[5];
    const float* bnb = (const float*)d_in[6];
    float* out = (float*)d_out;

    if (ws_size < WS_NEED) return;

    char* ws = (char*)d_ws;
    u16*   WT    = (u16*)(ws + WT_B);
    float* stats = (float*)(ws + STATS_B);
    u16*   xs0   = (u16*)(ws + XS0_B);
    u16*   x1    = (u16*)(ws + X1_B);
    u16*   x2    = (u16*)(ws + X2_B);
    u16*   h1s0  = (u16*)(ws + H1S0_B);
    u16*   h1s1  = (u16*)(ws + H1S1_B);
    u16*   h1s2  = (u16*)(ws + H1S2_B);
    float* y0f   = (float*)(ws + Y0F_B);
    u16*   y1    = (u16*)(ws + Y1_B);
    u16*   y2    = (u16*)(ws + Y2_B);
    u16*   h2s0  = (u16*)d_out;
    u16*   h2s1  = h2s0 + 16777216;
    u16*   h2s2  = h2s0 + 41943040;

    k_prep <<<5891, 256, 0, stream>>>(w1, w2, w3, wb, WT, stats);
    k_xconv<<<15360, 256, 0, stream>>>(x, xs0, x1, x2);

    for (int c = 0; c < NROW / CM; ++c) {
        size_t r0 = (size_t)c * CM;
        // L1s0: (h,h)TwoSum + (m,h),(h,m),(m,m),(l,h),(h,l)
        k_gemm<2, 3, true, false><<<512, 256, 0, stream>>>(
            xs0 + r0 * 768, 0L, 30, 768,
            256, 2, 24, 580u, 2128u, WT + 0, 768,
            nullptr, 0L, 30, 64, 64, 0, 0u, 0u, nullptr, 64,
            24, 4,
            h1s0, nullptr, 0L, 30, 1024, 512, 3);
        // L1s1: (h,h),(l,h),(h,m)
        k_gemm<4, 4, false, false><<<384, 256, 0, stream>>>(
            x1 + r0 * 256, 8388608L, 13, 256,
            128, 1, 6, 4u, 16u, WT + 393216, 256,
            nullptr, 0L, 30, 64, 64, 0, 0u, 0u, nullptr, 64,
            6, 0,
            h1s1, nullptr, 4194304L, 13, 512, 256, 1);
        // L1s2
        k_gemm<4, 4, false, false><<<320, 256, 0, stream>>>(
            x2 + r0 * 128, 4194304L, 13, 128,
            64, 0, 3, 4u, 16u, WT + 458752, 128,
            nullptr, 0L, 30, 64, 64, 0, 0u, 0u, nullptr, 64,
            3, 0,
            h1s2, nullptr, 2097152L, 13, 256, 128, 0);
        k_normact<3, true><<<1024, 256, 0, stream>>>(h1s1, 4194304L, 5, 256, 262144L);
        k_normact<5, true><<<512,  256, 0, stream>>>(h1s2, 2097152L, 4, 128, 131072L);
        // L2s0
        k_gemm<4, 2, false, false><<<256, 256, 0, stream>>>(
            h1s0, 0L, 30, 1024,
            512, 3, 24, 4u, 16u, WT + 475136, 1024,
            nullptr, 0L, 30, 64, 64, 0, 0u, 0u, nullptr, 64,
            24, 0,
            h2s0 + r0 * 512, nullptr, 0L, 30, 512, 0, 2);
        // L2s1
        k_gemm<4, 0, false, false><<<384, 256, 0, stream>>>(
            h1s1, 4194304L, 13, 512,
            256, 2, 12, 4u, 16u, WT + 999424, 512,
            nullptr, 0L, 30, 64, 64, 0, 0u, 0u, nullptr, 64,
            12, 0,
            h2s1 + r0 * 256, nullptr, 8388608L, 13, 256, 0, 1);
        // L2s2
        k_gemm<4, 0, false, false><<<320, 256, 0, stream>>>(
            h1s2, 2097152L, 13, 256,
            128, 1, 6, 4u, 16u, WT + 1130496, 256,
            nullptr, 0L, 30, 64, 64, 0, 0u, 0u, nullptr, 64,
            6, 0,
            h2s2 + r0 * 128, nullptr, 4194304L, 13, 128, 0, 0);
    }
    k_normact<3, false><<<4096, 256, 0, stream>>>(h2s1, 8388608L, 5, 256, 1048576L);
    k_normact<5, false><<<2048, 256, 0, stream>>>(h2s2, 4194304L, 4, 128, 524288L);

    // L3 + bypass
    k_gemm<4, 1, false, true><<<512, 256, 0, stream>>>(
        h2s0, 0L, 30, 512,
        512, 3, 8, 0u, 0u, WT + 1163264, 512,
        xs0, 0L, 30, 768,
        256, 2, 4u, 16u, WT + 1335296, 512,
        20, 0,
        nullptr, y0f, 0L, 30, 256, 0, 1);
    k_gemm<4, 0, false, true><<<768, 256, 0, stream>>>(
        h2s1, 8388608L, 15, 256,
        256, 2, 4, 0u, 0u, WT + 1294336, 256,
        x1, 8388608L, 15, 256,
        128, 1, 4u, 16u, WT + 1466368, 256,
        10, 0,
        y1, nullptr, 4194304L, 15, 128, 0, 0);
    k_gemm<2, 0, false, true><<<1280, 256, 0, stream>>>(
        h2s2, 4194304L, 15, 128,
        128, 1, 2, 0u, 0u, WT + 1327104, 128,
        x2, 4194304L, 15, 128,
        64, 0, 4u, 16u, WT + 1499136, 128,
        5, 0,
        y2, nullptr, 2097152L, 15, 64, 0, 0);

    k_stats  <<<dim3(64, 3), 256, 0, stream>>>(y0f, y1, y2, stats);
    k_bnapply<<<32768, 448, 0, stream>>>(y0f, y1, y2, stats, bnw, bnb, out);
}

// Round 9
// 1097.697 us; speedup vs baseline: 1.4424x; 1.2416x over previous
//
#include <hip/hip_runtime.h>
#include <cstddef>
#include <cstdint>

#define DEVINL __device__ __forceinline__
typedef unsigned short u16;
typedef __attribute__((ext_vector_type(8))) short short8;
typedef __attribute__((ext_vector_type(4))) float f32x4;
#define MFMA16 __builtin_amdgcn_mfma_f32_16x16x32_bf16

constexpr int NROW = 32768;
constexpr int CM   = 8192;           // chunk rows (4 chunks)

// ---------- ws byte offsets (identical to validated round-5 layout) ----------
constexpr size_t WT_B    = 0;          // 1,507,328 u16
constexpr size_t STATS_B = 3014656;    // 704 f32
constexpr size_t XS0_B   = 3017728;    // [32768][768] u16  (xh|xm|xl)
constexpr size_t X1_B    = 53349376;   // [3][32768][256] u16 ([h|l])
constexpr size_t X2_B    = 103681024;  // [5][32768][128] u16 ([h|l])
constexpr size_t H1S0_B  = 145624064;  // [8192][1024] u16 ([h|l])
constexpr size_t H1S1_B  = 162401280;  // [3][8192][512] u16 ([h|l])
constexpr size_t H1S2_B  = 187567104;  // [5][8192][256] u16 ([h|l])
constexpr size_t Y0F_B   = 145624064;  // [32768][256] f32 (overlay after chunk loop)
constexpr size_t Y1_B    = 179178496;  // [3][32768][128] bf16
constexpr size_t Y2_B    = 204344320;  // [5][32768][64] bf16
constexpr size_t WS_NEED = 225315840;

DEVINL u16 f2bf(float f) { union { float f; unsigned u; } c; c.f = f;
    unsigned r = (c.u + 0x7fffu + ((c.u >> 16) & 1u)) >> 16; return (u16)r; }
DEVINL float bf2f(u16 b) { union { unsigned u; float f; } c; c.u = ((unsigned)b) << 16; return c.f; }
DEVINL short8 ld8(const u16* p) { return *(const short8*)p; }

DEVINL void gload16(const u16* g, u16* l) {
    __builtin_amdgcn_global_load_lds(
        (const __attribute__((address_space(1))) unsigned*)g,
        (__attribute__((address_space(3))) unsigned*)l, 16, 0, 0);
}

// ---------------- prep (verbatim round 5) ----------------
__global__ void k_prep(const float* __restrict__ w1, const float* __restrict__ w2,
                       const float* __restrict__ w3, const float* __restrict__ wb,
                       u16* __restrict__ WT, float* __restrict__ stats)
{
    int t = blockIdx.x * 256 + threadIdx.x;
    if (t < 1507328) {
        const float iA = 0.08838834764831845f;   // 1/sqrt(128)
        const float iB = 0.044194173824159216f;  // 1/sqrt(512)
        const int   beg[12]  = {0,393216,458752,475136,999424,1130496,1163264,1294336,1327104,1335296,1466368,1499136};
        const int   rowW[12] = {768,256,128,1024,512,256,512,256,128,512,256,128};
        const int   l2K[12]  = {8,7,6,9,8,7,9,8,7,8,7,6};
        const int   srco[12] = {0,131072,163840,0,262144,327680,0,131072,163840,0,65536,81920};
        const int   arr[12]  = {0,0,0,1,1,1,2,2,2,3,3,3};
        const int   ld[12]   = {512,256,128,512,256,128,256,128,64,256,128,64};
        const float scl[12]  = {0.0625f,iA,0.125f,iB,0.0625f,iA,iB,0.0625f,iA,0.0625f,iA,0.125f};
        int s = 0;
        #pragma unroll
        for (int i = 1; i < 12; ++i) s += (t >= beg[i]) ? 1 : 0;
        int e    = t - beg[s];
        int v    = e / rowW[s];
        int rem  = e - v * rowW[s];
        int limb = rem >> l2K[s];
        int u    = rem & ((1 << l2K[s]) - 1);
        const float* srcs[4] = {w1, w2, w3, wb};
        float val = srcs[arr[s]][srco[s] + u * ld[s] + v] * scl[s];
        u16 h = f2bf(val);  float r1 = val - bf2f(h);
        u16 m = f2bf(r1);   float r2 = r1 - bf2f(m);
        WT[t] = (limb == 0) ? h : (limb == 1) ? m : f2bf(r2);
    } else {
        int q = t - 1507328;
        if (q < 704) stats[q] = 0.f;
    }
}

// ---------------- x -> limb planes, LDS-coalesced version ----------------
__global__ __launch_bounds__(256) void k_xconv(const float* __restrict__ x,
    u16* __restrict__ xs0, u16* __restrict__ x1, u16* __restrict__ x2)
{
    __shared__ float xl[15360];           // 16 rows x 960
    int t = threadIdx.x;
    int n0 = blockIdx.x * 16;             // grid 2048
    const float* src = x + (size_t)n0 * 960;
    #pragma unroll
    for (int i = 0; i < 15; ++i) {
        float4 v = *(const float4*)(src + (size_t)(i * 256 + t) * 4);
        *(float4*)&xl[(i * 256 + t) * 4] = v;
    }
    __syncthreads();
    #pragma unroll
    for (int k = 0; k < 17; ++k) {
        int id = k * 256 + t;
        float f[8]; u16* dst; int limb;
        if (id < 1536) {                   // sec0: 3 limbs x 16 rows x 32 groups
            limb = id >> 9; int rem = id & 511;
            int r = rem >> 5, g = rem & 31;
            #pragma unroll
            for (int j = 0; j < 8; ++j) f[j] = xl[r * 960 + g * 8 + j];
            dst = xs0 + (size_t)(n0 + r) * 768 + limb * 256 + g * 8;
        } else if (id < 3072) {            // sec1: 2 limbs x 3 planes x 16 rows x 16 groups
            int id1 = id - 1536;
            limb = id1 / 768; int rem = id1 % 768;
            int i = rem >> 8; int rem2 = rem & 255;
            int r = rem2 >> 4, g = rem2 & 15;
            #pragma unroll
            for (int j = 0; j < 8; ++j) f[j] = xl[r * 960 + 256 + (g * 8 + j) * 3 + i];
            dst = x1 + (size_t)i * 8388608 + (size_t)(n0 + r) * 256 + limb * 128 + g * 8;
        } else {                           // sec2: 2 limbs x 5 planes x 16 rows x 8 groups
            int id2 = id - 3072;
            limb = id2 / 640; int rem = id2 % 640;
            int i = rem >> 7; int rem2 = rem & 127;
            int r = rem2 >> 3, g = rem2 & 7;
            #pragma unroll
            for (int j = 0; j < 8; ++j) f[j] = xl[r * 960 + 640 + (g * 8 + j) * 5 + i];
            dst = x2 + (size_t)i * 4194304 + (size_t)(n0 + r) * 128 + limb * 64 + g * 8;
        }
        short8 o;
        #pragma unroll
        for (int j = 0; j < 8; ++j) {
            float v = f[j];
            u16 h = f2bf(v);
            if (limb == 0) { o[j] = (short)h; }
            else {
                float r1 = v - bf2f(h);
                u16 m = f2bf(r1);
                o[j] = (limb == 1) ? (short)m : (short)f2bf(r1 - bf2f(m));
            }
        }
        *(short8*)dst = o;
    }
}

// ---------------- merged GEMM machinery ----------------
struct SecDesc {
    const u16* A1; const u16* A2; const u16* B1; const u16* B2;
    u16* outB; float* outF;
    long A1ps, A2ps, Ops;
    unsigned a1map, b1map, a2map, b2map;
    int A1cmb, A1rs, K1, k1t, T1, B1rs;
    int A2cmb, A2rs, K2, k2t, B2rs;
    int Stot, tsTiles, Ocmb, Ors, loOff, nrb, bid0;
};
struct Sec3 { SecDesc d[3]; };

// EP: 0=bf16  1=f32  2=sig bf16  3=sig split  4=plain split
template<int NT, int EP, bool TS, bool SEG2>
DEVINL void gemm_body(u16* lds, const SecDesc& d, int bid)
{
    constexpr int BN = NT * 32;
    int idx = bid - d.bid0;
    int rb = idx % d.nrb, cb = idx / d.nrb;
    int rb128 = rb << 7;
    int tix = threadIdx.x, lane = tix & 63, w = tix >> 6;
    int wm64 = (w >> 1) << 6, wn = w & 1;

    const u16* a1row = d.A1 + (size_t)(rb128 >> d.A1cmb) * d.A1ps
                            + (size_t)(rb128 & ((1 << d.A1cmb) - 1)) * (size_t)d.A1rs;
    const u16* a2row = nullptr;
    if constexpr (SEG2)
        a2row = d.A2 + (size_t)(rb128 >> d.A2cmb) * d.A2ps
                     + (size_t)(rb128 & ((1 << d.A2cmb) - 1)) * (size_t)d.A2rs;

    auto stage = [&](int t, int buf) {
        const u16* art; int rs, col0;
        if (!SEG2 || t < d.T1) {
            int sg = t >> d.k1t, off = (t & ((1 << d.k1t) - 1)) << 6;
            art = a1row; rs = d.A1rs;
            col0 = (int)((d.a1map >> (2 * sg)) & 3u) * d.K1 + off;
        } else {
            int tt = t - d.T1;
            int sg = tt >> d.k2t, off = (tt & ((1 << d.k2t) - 1)) << 6;
            art = a2row; rs = d.A2rs;
            col0 = (int)((d.a2map >> (2 * sg)) & 3u) * d.K2 + off;
        }
        #pragma unroll
        for (int i = 0; i < 4; ++i) {
            int seg = (w << 2) | i;
            int tr  = (seg << 3) + (lane >> 3);
            int sl  = lane & 7;
            gload16(art + (size_t)tr * rs + col0 + ((sl ^ (tr & 7)) << 3),
                    lds + buf * 8192 + seg * 512);
        }
    };

    f32x4 z = {0.f, 0.f, 0.f, 0.f};
    f32x4 acc[4][NT], S[4][NT], E[4][NT];
    #pragma unroll
    for (int mt = 0; mt < 4; ++mt)
        #pragma unroll
        for (int nt = 0; nt < NT; ++nt) { acc[mt][nt] = z; if constexpr (TS) { S[mt][nt] = z; E[mt][nt] = z; } }

    stage(0, 0);
    stage(1, 1);
    int colbase = cb * BN + wn * (NT * 16) + (lane & 15);
    int cur = 0;
    for (int s = 0; s < d.Stot; ++s) {
        // B loads first
        const u16* bp; int brs, bcol;
        if (!SEG2 || s < d.T1) {
            int sg = s >> d.k1t;
            bcol = (int)((d.b1map >> (2 * sg)) & 3u) * d.K1 + ((s & ((1 << d.k1t) - 1)) << 6);
            bp = d.B1; brs = d.B1rs;
        } else {
            int tt = s - d.T1, sg = tt >> d.k2t;
            bcol = (int)((d.b2map >> (2 * sg)) & 3u) * d.K2 + ((tt & ((1 << d.k2t) - 1)) << 6);
            bp = d.B2; brs = d.B2rs;
        }
        short8 breg[NT][2];
        #pragma unroll
        for (int nt = 0; nt < NT; ++nt)
            #pragma unroll
            for (int h = 0; h < 2; ++h)
                breg[nt][h] = ld8(bp + (size_t)(colbase + nt * 16) * brs + bcol + h * 32 + ((lane >> 4) << 3));

        int nb = cur + 2; if (nb >= 3) nb -= 3;
        if (s + 2 < d.Stot) {
            stage(s + 2, nb);
            // stage(s) has >=12 newer VMEM ops -> guaranteed drained; keep pipeline in flight
            asm volatile("s_waitcnt vmcnt(8)" ::: "memory");
        } else {
            asm volatile("s_waitcnt vmcnt(0)" ::: "memory");
        }
        asm volatile("s_barrier" ::: "memory");   // pre-read: all waves' stage(s) landed

        const u16* lbuf = lds + cur * 8192;
        bool tsT = TS && (s < d.tsTiles);
        #pragma unroll
        for (int h = 0; h < 2; ++h) {
            short8 a[4];
            #pragma unroll
            for (int mt = 0; mt < 4; ++mt) {
                int tr = wm64 + mt * 16 + (lane & 15);
                int slot = h * 4 + (lane >> 4);
                a[mt] = *(const short8*)&lbuf[tr * 64 + ((slot ^ (tr & 7)) << 3)];
            }
            if (tsT) {
                #pragma unroll
                for (int mt = 0; mt < 4; ++mt)
                    #pragma unroll
                    for (int nt = 0; nt < NT; ++nt) {
                        f32x4 dd = MFMA16(a[mt], breg[nt][h], z, 0, 0, 0);
                        #pragma unroll
                        for (int r = 0; r < 4; ++r) {
                            float aa = S[mt][nt][r], bb = dd[r];
                            float sm = aa + bb;
                            float tt2 = sm - aa;
                            float er = (aa - (sm - tt2)) + (bb - tt2);
                            S[mt][nt][r] = sm;
                            E[mt][nt][r] += er;
                        }
                    }
            } else {
                #pragma unroll
                for (int mt = 0; mt < 4; ++mt)
                    #pragma unroll
                    for (int nt = 0; nt < NT; ++nt)
                        acc[mt][nt] = MFMA16(a[mt], breg[nt][h], acc[mt][nt], 0, 0, 0);
            }
        }
        asm volatile("s_barrier" ::: "memory");   // post-read: protect buf reuse (WAR)
        cur = (cur + 1 == 3) ? 0 : cur + 1;
    }

    size_t obase = (size_t)(rb128 >> d.Ocmb) * d.Ops + (size_t)(rb128 & ((1 << d.Ocmb) - 1)) * (size_t)d.Ors;
    #pragma unroll
    for (int mt = 0; mt < 4; ++mt) {
        #pragma unroll
        for (int r = 0; r < 4; ++r) {
            int lrow = wm64 + mt * 16 + ((lane >> 4) << 2) + r;
            size_t ro = obase + (size_t)lrow * d.Ors;
            #pragma unroll
            for (int nt = 0; nt < NT; ++nt) {
                int colg = cb * BN + wn * (NT * 16) + nt * 16 + (lane & 15);
                float p = acc[mt][nt][r];
                if constexpr (TS) p = S[mt][nt][r] + (E[mt][nt][r] + p);
                if constexpr (EP == 1) {
                    d.outF[ro + colg] = p;
                } else {
                    float v = p;
                    if constexpr (EP == 2 || EP == 3) {
                        float nrm = sqrtf(p * p + 1e-8f);
                        v = p / ((1.0f + expf(-nrm)) * nrm);
                    }
                    u16 hi = f2bf(v);
                    d.outB[ro + colg] = hi;
                    if constexpr (EP == 3 || EP == 4)
                        d.outB[ro + colg + d.loOff] = f2bf(v - bf2f(hi));
                }
            }
        }
    }
}

__global__ __launch_bounds__(256) void k_L1(Sec3 ds)
{
    __shared__ u16 lds[24576];
    int bid = blockIdx.x;
    if (bid < ds.d[1].bid0)      gemm_body<2, 3, true,  false>(lds, ds.d[0], bid);
    else if (bid < ds.d[2].bid0) gemm_body<4, 4, false, false>(lds, ds.d[1], bid);
    else                         gemm_body<4, 4, false, false>(lds, ds.d[2], bid);
}
__global__ __launch_bounds__(256) void k_L2(Sec3 ds)
{
    __shared__ u16 lds[24576];
    int bid = blockIdx.x;
    if (bid < ds.d[1].bid0)      gemm_body<4, 2, false, false>(lds, ds.d[0], bid);
    else if (bid < ds.d[2].bid0) gemm_body<4, 0, false, false>(lds, ds.d[1], bid);
    else                         gemm_body<4, 0, false, false>(lds, ds.d[2], bid);
}
__global__ __launch_bounds__(256) void k_L3(Sec3 ds)
{
    __shared__ u16 lds[24576];
    int bid = blockIdx.x;
    if (bid < ds.d[1].bid0)      gemm_body<4, 1, false, true>(lds, ds.d[0], bid);
    else if (bid < ds.d[2].bid0) gemm_body<4, 0, false, true>(lds, ds.d[1], bid);
    else                         gemm_body<2, 0, false, true>(lds, ds.d[2], bid);
}

// ---------------- norm-act for l>0 planes (merged, split-aware) ----------------
template<int C, bool SPL>
DEVINL void na_body(u16* __restrict__ buf, long PS, int l2g, int halfW, long total8, long bb)
{
    long idx = bb * 256 + threadIdx.x;
    if (idx >= total8) return;
    long r  = idx >> l2g;
    int  cg = (int)(idx & ((1 << l2g) - 1));
    int  W  = SPL ? (halfW << 1) : halfW;
    size_t off = (size_t)r * W + (size_t)cg * 8;
    float f[C][8];
    #pragma unroll
    for (int i = 0; i < C; ++i) {
        short8 h = ld8(buf + (size_t)i * PS + off);
        if constexpr (SPL) {
            short8 l = ld8(buf + (size_t)i * PS + off + halfW);
            #pragma unroll
            for (int j = 0; j < 8; ++j) f[i][j] = bf2f((u16)h[j]) + bf2f((u16)l[j]);
        } else {
            #pragma unroll
            for (int j = 0; j < 8; ++j) f[i][j] = bf2f((u16)h[j]);
        }
    }
    #pragma unroll
    for (int j = 0; j < 8; ++j) {
        float s2 = 1e-8f;
        #pragma unroll
        for (int i = 0; i < C; ++i) s2 += f[i][j] * f[i][j];
        float nrm = sqrtf(s2);
        float scl = 1.0f / ((1.0f + __expf(-nrm)) * nrm);
        #pragma unroll
        for (int i = 0; i < C; ++i) f[i][j] *= scl;
    }
    #pragma unroll
    for (int i = 0; i < C; ++i) {
        short8 oh, ol;
        #pragma unroll
        for (int j = 0; j < 8; ++j) {
            u16 hi = f2bf(f[i][j]);
            oh[j] = (short)hi;
            if constexpr (SPL) ol[j] = (short)f2bf(f[i][j] - bf2f(hi));
        }
        *(short8*)(buf + (size_t)i * PS + off) = oh;
        if constexpr (SPL) *(short8*)(buf + (size_t)i * PS + off + halfW) = ol;
    }
}

template<bool SPL>
__global__ __launch_bounds__(256) void k_na(
    u16* b3, long PS3, int l2g3, int hw3, long t83,
    u16* b5, long PS5, int l2g5, int hw5, long t85, int blk5)
{
    int bid = blockIdx.x;
    if (bid < blk5) na_body<3, SPL>(b3, PS3, l2g3, hw3, t83, bid);
    else            na_body<5, SPL>(b5, PS5, l2g5, hw5, t85, bid - blk5);
}

// ---------------- BN stats ----------------
__global__ void k_stats(const float* __restrict__ y0f, const u16* __restrict__ y1,
                        const u16* __restrict__ y2, float* __restrict__ stats)
{
    int sec = blockIdx.y, t = threadIdx.x;
    int r0 = blockIdx.x * 256;
    float sm = 0.f, sq = 0.f;
    if (sec == 0) {
        int v = t;
        for (int r = r0; r < r0 + 256; ++r) {
            float val = y0f[(size_t)r * 256 + v];
            sm += val; sq += val * val;
        }
        atomicAdd(&stats[v], sm);
        atomicAdd(&stats[256 + v], sq);
    } else if (sec == 1) {
        int v = t & 127, sub = t >> 7;
        for (int r = r0 + sub; r < r0 + 256; r += 2)
            #pragma unroll
            for (int p = 0; p < 3; ++p) {
                float val = bf2f(y1[(size_t)p * 4194304 + (size_t)r * 128 + v]);
                sq += val * val;
            }
        __shared__ float S2[256];
        S2[t] = sq; __syncthreads();
        if (t < 128) atomicAdd(&stats[512 + v], sq + S2[t + 128]);
    } else {
        int v = t & 63, sub = t >> 6;
        for (int r = r0 + sub; r < r0 + 256; r += 4)
            #pragma unroll
            for (int p = 0; p < 5; ++p) {
                float val = bf2f(y2[(size_t)p * 2097152 + (size_t)r * 64 + v]);
                sq += val * val;
            }
        __shared__ float S2[256];
        S2[t] = sq; __syncthreads();
        if (t < 64) atomicAdd(&stats[640 + v], sq + S2[t + 64] + S2[t + 128] + S2[t + 192]);
    }
}

// ---------------- BN apply (verbatim round 5) ----------------
__global__ __launch_bounds__(448) void k_bnapply(
    const float* __restrict__ y0f, const u16* __restrict__ y1, const u16* __restrict__ y2,
    const float* __restrict__ stats, const float* __restrict__ bnw, const float* __restrict__ bnb,
    float* __restrict__ out)
{
    int n = blockIdx.x, t = threadIdx.x;
    const float invN = 1.f / 32768.f;
    if (t < 256) {
        float mu  = stats[t] * invN;
        float var = stats[256 + t] * invN - mu * mu;
        float a   = bnw[t] * rsqrtf(var + 1e-5f);
        out[(size_t)n * 960 + t] = (y0f[(size_t)n * 256 + t] - mu) * a + bnb[t];
    } else if (t < 384) {
        int v = t - 256;
        float a = bnw[256 + v] * rsqrtf(stats[512 + v] * (invN / 3.f) + 1e-5f);
        #pragma unroll
        for (int i = 0; i < 3; ++i)
            out[(size_t)n * 960 + 256 + v * 3 + i] =
                bf2f(y1[(size_t)i * 4194304 + (size_t)n * 128 + v]) * a;
    } else {
        int v = t - 384;
        float a = bnw[384 + v] * rsqrtf(stats[640 + v] * (invN / 5.f) + 1e-5f);
        #pragma unroll
        for (int i = 0; i < 5; ++i)
            out[(size_t)n * 960 + 640 + v * 5 + i] =
                bf2f(y2[(size_t)i * 2097152 + (size_t)n * 64 + v]) * a;
    }
}

static SecDesc mk(const u16* A1, long A1ps, int A1cmb, int A1rs,
                  int K1, int k1t, int T1, unsigned a1map, unsigned b1map,
                  const u16* B1, int B1rs,
                  const u16* A2, long A2ps, int A2cmb, int A2rs,
                  int K2, int k2t, unsigned a2map, unsigned b2map,
                  const u16* B2, int B2rs,
                  int Stot, int tsTiles,
                  u16* outB, float* outF, long Ops, int Ocmb, int Ors, int loOff,
                  int nrb, int bid0)
{
    SecDesc d;
    d.A1 = A1; d.A1ps = A1ps; d.A1cmb = A1cmb; d.A1rs = A1rs;
    d.K1 = K1; d.k1t = k1t; d.T1 = T1; d.a1map = a1map; d.b1map = b1map;
    d.B1 = B1; d.B1rs = B1rs;
    d.A2 = A2; d.A2ps = A2ps; d.A2cmb = A2cmb; d.A2rs = A2rs;
    d.K2 = K2; d.k2t = k2t; d.a2map = a2map; d.b2map = b2map;
    d.B2 = B2; d.B2rs = B2rs;
    d.Stot = Stot; d.tsTiles = tsTiles;
    d.outB = outB; d.outF = outF; d.Ops = Ops; d.Ocmb = Ocmb; d.Ors = Ors; d.loOff = loOff;
    d.nrb = nrb; d.bid0 = bid0;
    return d;
}

extern "C" void kernel_launch(void* const* d_in, const int* in_sizes, int n_in,
                              void* d_out, int out_size, void* d_ws, size_t ws_size,
                              hipStream_t stream)
{
    const float* x   = (const float*)d_in[0];
    const float* w1  = (const float*)d_in[1];
    const float* w2  = (const float*)d_in[2];
    const float* w3  = (const float*)d_in[3];
    const float* wb  = (const float*)d_in[4];
    const float* bnw = (const float*)d_in[5];
    const float* bnb = (const float*)d_in[6];
    float* out = (float*)d_out;

    if (ws_size < WS_NEED) return;

    char* ws = (char*)d_ws;
    u16*   WT    = (u16*)(ws + WT_B);
    float* stats = (float*)(ws + STATS_B);
    u16*   xs0   = (u16*)(ws + XS0_B);
    u16*   x1    = (u16*)(ws + X1_B);
    u16*   x2    = (u16*)(ws + X2_B);
    u16*   h1s0  = (u16*)(ws + H1S0_B);
    u16*   h1s1  = (u16*)(ws + H1S1_B);
    u16*   h1s2  = (u16*)(ws + H1S2_B);
    float* y0f   = (float*)(ws + Y0F_B);
    u16*   y1    = (u16*)(ws + Y1_B);
    u16*   y2    = (u16*)(ws + Y2_B);
    u16*   h2s0  = (u16*)d_out;
    u16*   h2s1  = h2s0 + 16777216;
    u16*   h2s2  = h2s0 + 41943040;

    k_prep <<<5891, 256, 0, stream>>>(w1, w2, w3, wb, WT, stats);
    k_xconv<<<2048, 256, 0, stream>>>(x, xs0, x1, x2);

    for (int c = 0; c < NROW / CM; ++c) {
        size_t r0 = (size_t)c * CM;
        Sec3 dl1;
        dl1.d[0] = mk(xs0 + r0 * 768, 0L, 30, 768, 256, 2, 24, 580u, 2128u, WT + 0, 768,
                      nullptr, 0L, 30, 64, 64, 0, 0u, 0u, nullptr, 64,
                      24, 4, h1s0, nullptr, 0L, 30, 1024, 512, 64, 0);
        dl1.d[1] = mk(x1 + r0 * 256, 8388608L, 13, 256, 128, 1, 6, 4u, 16u, WT + 393216, 256,
                      nullptr, 0L, 30, 64, 64, 0, 0u, 0u, nullptr, 64,
                      6, 0, h1s1, nullptr, 4194304L, 13, 512, 256, 192, 512);
        dl1.d[2] = mk(x2 + r0 * 128, 4194304L, 13, 128, 64, 0, 3, 4u, 16u, WT + 458752, 128,
                      nullptr, 0L, 30, 64, 64, 0, 0u, 0u, nullptr, 64,
                      3, 0, h1s2, nullptr, 2097152L, 13, 256, 128, 320, 896);
        k_L1<<<1216, 256, 0, stream>>>(dl1);

        k_na<true><<<1536, 256, 0, stream>>>(h1s1, 4194304L, 5, 256, 262144L,
                                             h1s2, 2097152L, 4, 128, 131072L, 1024);

        Sec3 dl2;
        dl2.d[0] = mk(h1s0, 0L, 30, 1024, 512, 3, 24, 4u, 16u, WT + 475136, 1024,
                      nullptr, 0L, 30, 64, 64, 0, 0u, 0u, nullptr, 64,
                      24, 0, h2s0 + r0 * 512, nullptr, 0L, 30, 512, 0, 64, 0);
        dl2.d[1] = mk(h1s1, 4194304L, 13, 512, 256, 2, 12, 4u, 16u, WT + 999424, 512,
                      nullptr, 0L, 30, 64, 64, 0, 0u, 0u, nullptr, 64,
                      12, 0, h2s1 + r0 * 256, nullptr, 8388608L, 13, 256, 0, 192, 256);
        dl2.d[2] = mk(h1s2, 2097152L, 13, 256, 128, 1, 6, 4u, 16u, WT + 1130496, 256,
                      nullptr, 0L, 30, 64, 64, 0, 0u, 0u, nullptr, 64,
                      6, 0, h2s2 + r0 * 128, nullptr, 4194304L, 13, 128, 0, 320, 640);
        k_L2<<<960, 256, 0, stream>>>(dl2);
    }

    k_na<false><<<6144, 256, 0, stream>>>(h2s1, 8388608L, 5, 256, 1048576L,
                                          h2s2, 4194304L, 4, 128, 524288L, 4096);

    Sec3 dl3;
    dl3.d[0] = mk(h2s0, 0L, 30, 512, 512, 3, 8, 0u, 0u, WT + 1163264, 512,
                  xs0, 0L, 30, 768, 256, 2, 4u, 16u, WT + 1335296, 512,
                  20, 0, nullptr, y0f, 0L, 30, 256, 0, 256, 0);
    dl3.d[1] = mk(h2s1, 8388608L, 15, 256, 256, 2, 4, 0u, 0u, WT + 1294336, 256,
                  x1, 8388608L, 15, 256, 128, 1, 4u, 16u, WT + 1466368, 256,
                  10, 0, y1, nullptr, 4194304L, 15, 128, 0, 768, 512);
    dl3.d[2] = mk(h2s2, 4194304L, 15, 128, 128, 1, 2, 0u, 0u, WT + 1327104, 128,
                  x2, 4194304L, 15, 128, 64, 0, 4u, 16u, WT + 1499136, 128,
                  5, 0, y2, nullptr, 2097152L, 15, 64, 0, 1280, 1280);
    k_L3<<<2560, 256, 0, stream>>>(dl3);

    k_stats  <<<dim3(128, 3), 256, 0, stream>>>(y0f, y1, y2, stats);
    k_bnapply<<<32768, 448, 0, stream>>>(y0f, y1, y2, stats, bnw, bnb, out);
}